// Round 7
// baseline (14662.488 us; speedup 1.0000x reference)
//
#include <hip/hip_runtime.h>
#include <hip/hip_bf16.h>
#include <cstdint>

#define BB 128
#define LL 1024
#define VV 512
#define HH 512
#define G3 1536
#define CC 20
#define VH (VV*HH)
#define BH (BB*HH)

typedef unsigned short u16;
typedef unsigned int   u32;
typedef __attribute__((ext_vector_type(8))) __bf16 bf16x8;
typedef __attribute__((ext_vector_type(4))) float  f32x4;

__device__ __forceinline__ float bf2f(u16 x){
  u32 u = ((u32)x) << 16; float f; __builtin_memcpy(&f, &u, 4); return f;
}
__device__ __forceinline__ u16 f2bf(float f){
  u32 u; __builtin_memcpy(&u, &f, 4);
  u32 r = (u + 0x7fffu + ((u >> 16) & 1u)) >> 16;
  return (u16)r;
}
__device__ __forceinline__ bf16x8 ld8(const u16* p){
  bf16x8 v; __builtin_memcpy(&v, p, 16); return v;
}
__device__ __forceinline__ uint4 ld4u(const void* p){
  uint4 v; __builtin_memcpy(&v, p, 16); return v;
}
__device__ __forceinline__ void st4u(void* p, uint4 v){
  __builtin_memcpy(p, &v, 16);
}
__device__ __forceinline__ void add8(float* a, uint4 w){
  a[0] += bf2f((u16)(w.x & 0xffff)); a[1] += bf2f((u16)(w.x >> 16));
  a[2] += bf2f((u16)(w.y & 0xffff)); a[3] += bf2f((u16)(w.y >> 16));
  a[4] += bf2f((u16)(w.z & 0xffff)); a[5] += bf2f((u16)(w.z >> 16));
  a[6] += bf2f((u16)(w.w & 0xffff)); a[7] += bf2f((u16)(w.w >> 16));
}

// -------- float dtype probe: conv_b uniform +-0.0255 -> bf16 exp field <= 121 always.
// If buffer is fp32, low-half u16 words have ~uniform exponent bits -> certain hit >=126.
__global__ __launch_bounds__(256) void detect_dtype(const u16* __restrict__ cb,
                                                    u32* __restrict__ flag){
  __shared__ u32 red[256];
  int tid = threadIdx.x;
  u32 bad = 0;
  for (int i = tid; i < 512; i += 256){
    u32 e = ((u32)cb[i] >> 7) & 0xFF;
    if (e >= 126) bad = 1;
  }
  red[tid] = bad; __syncthreads();
  for (int s = 128; s > 0; s >>= 1){
    if (tid < s) red[tid] |= red[tid + s];
    __syncthreads();
  }
  if (tid == 0) *flag = red[0];   // 0 = floats bf16, 1 = floats fp32
}

// -------- int width probe (kept): int64 tokens -> odd int32 words all zero.
__global__ __launch_bounds__(256) void detect_int(const int* __restrict__ x,
                                                  u32* __restrict__ flag){
  __shared__ u32 red[256];
  int tid = threadIdx.x;
  u32 nz = 0;
  for (int i = tid; i < 65536; i += 256){
    if (x[2 * i + 1] != 0) nz = 1;
  }
  red[tid] = nz; __syncthreads();
  for (int s = 128; s > 0; s >>= 1){
    if (tid < s) red[tid] |= red[tid + s];
    __syncthreads();
  }
  if (tid == 0) *flag = red[0];   // 1 = int32, 0 = int64
}

__global__ __launch_bounds__(256) void norm_x(const int* __restrict__ src,
    int* __restrict__ dst, const u32* __restrict__ flag){
  int i = blockIdx.x * 256 + threadIdx.x;
  if (i >= BB * LL) return;
  dst[i] = (*flag) ? src[i] : src[2 * i];   // int64 little-endian low word
}

__global__ __launch_bounds__(256) void norm_bf16(const void* __restrict__ src,
    u16* __restrict__ dst, int n, const u32* __restrict__ flag){
  int i = blockIdx.x * 256 + threadIdx.x;
  if (i >= n) return;
  if (*flag) dst[i] = f2bf(((const float*)src)[i]);
  else       dst[i] = ((const u16*)src)[i];
}
__global__ __launch_bounds__(256) void norm_f32(const void* __restrict__ src,
    float* __restrict__ dst, int n, const u32* __restrict__ flag){
  int i = blockIdx.x * 256 + threadIdx.x;
  if (i >= n) return;
  if (*flag) dst[i] = ((const float*)src)[i];
  else       dst[i] = bf2f(((const u16*)src)[i]);
}

// ---------------- phase 0: transpose conv_w copy (H,V,3) -> 3 tables (V,H) ------------
__global__ __launch_bounds__(256) void prep_tables(const u16* __restrict__ conv_w,
                                                   u16* __restrict__ tabs){
  int n = blockIdx.x * 256 + threadIdx.x;   // n = v*512 + h over V*H
  if (n >= VH) return;
  int v = n >> 9, h = n & 511;
  const u16* src = conv_w + ((size_t)h * VV + v) * 3;
  tabs[0 * VH + n] = src[0];
  tabs[1 * VH + n] = src[1];
  tabs[2 * VH + n] = src[2];
}

// ---------------- phase 1: embedding-sum + bias + ReLU -> seq chunk (Tc*128, H) bf16 ---
__global__ __launch_bounds__(256) void embed_kernel(const int* __restrict__ x,
    const u16* __restrict__ tabs, const u16* __restrict__ cwb,
    const float* __restrict__ cbf, u16* __restrict__ seq, int m_base){
  int ml = blockIdx.x * 4 + (threadIdx.x >> 6);   // local row within chunk
  int lane = threadIdx.x & 63;
  int m = m_base + ml;                             // global: m = l*128 + b
  int l = m >> 7, b = m & 127;
  int h0 = lane * 8;
  float a[8];
  #pragma unroll
  for (int j = 0; j < 8; ++j) a[j] = cbf[h0 + j];
  if (tabs){
    int t0 = x[b * LL + l];
    add8(a, ld4u(tabs + 1 * VH + (size_t)t0 * HH + h0));
    if (l > 0){
      int tm = x[b * LL + l - 1];
      add8(a, ld4u(tabs + 0 * VH + (size_t)tm * HH + h0));
    }
    if (l < LL - 1){
      int tp = x[b * LL + l + 1];
      add8(a, ld4u(tabs + 2 * VH + (size_t)tp * HH + h0));
    }
  } else {
    int t0 = x[b * LL + l];
    #pragma unroll
    for (int j = 0; j < 8; ++j) a[j] += bf2f(cwb[((size_t)(h0 + j) * VV + t0) * 3 + 1]);
    if (l > 0){
      int tm = x[b * LL + l - 1];
      #pragma unroll
      for (int j = 0; j < 8; ++j) a[j] += bf2f(cwb[((size_t)(h0 + j) * VV + tm) * 3 + 0]);
    }
    if (l < LL - 1){
      int tp = x[b * LL + l + 1];
      #pragma unroll
      for (int j = 0; j < 8; ++j) a[j] += bf2f(cwb[((size_t)(h0 + j) * VV + tp) * 3 + 2]);
    }
  }
  uint4 o;
  o.x = (u32)f2bf(fmaxf(a[0], 0.f)) | ((u32)f2bf(fmaxf(a[1], 0.f)) << 16);
  o.y = (u32)f2bf(fmaxf(a[2], 0.f)) | ((u32)f2bf(fmaxf(a[3], 0.f)) << 16);
  o.z = (u32)f2bf(fmaxf(a[4], 0.f)) | ((u32)f2bf(fmaxf(a[5], 0.f)) << 16);
  o.w = (u32)f2bf(fmaxf(a[6], 0.f)) | ((u32)f2bf(fmaxf(a[7], 0.f)) << 16);
  st4u(seq + (size_t)ml * HH + h0, o);
}

// ------- phase 2: gi_chunk(fp32) = seq_chunk @ w_ih^T + b_ih  (M=Tc*128,N=1536,K=512) --
__global__ __launch_bounds__(256) void gemm_gi(const u16* __restrict__ A,
                                               const u16* __restrict__ Bw,
                                               const float* __restrict__ bias,
                                               float* __restrict__ Cout){
  __shared__ u16 As[128 * 32];
  __shared__ u16 Bs[128 * 32];
  const int tid = threadIdx.x;
  const int wave = tid >> 6, lane = tid & 63;
  const int q = lane >> 4, ln = lane & 15;
  const int m0 = blockIdx.y * 128;
  const int n0 = blockIdx.x * 128;
  const int wm = (wave & 1) * 64, wn = (wave >> 1) * 64;

  f32x4 acc[4][4] = {};

  for (int kt = 0; kt < 16; ++kt){
    const int k0 = kt * 32;
    #pragma unroll
    for (int j = 0; j < 2; ++j){
      int v = j * 256 + tid;            // row = v>>2, col = (v&3)*8
      int row = v >> 2, col = (v & 3) * 8;
      uint4 av = ld4u(A  + (size_t)(m0 + row) * 512 + k0 + col);
      uint4 bv = ld4u(Bw + (size_t)(n0 + row) * 512 + k0 + col);
      st4u(&As[v * 8], av);
      st4u(&Bs[v * 8], bv);
    }
    __syncthreads();
    bf16x8 af[4], bf[4];
    #pragma unroll
    for (int mt = 0; mt < 4; ++mt)
      af[mt] = ld8(&As[(wm + mt * 16 + ln) * 32 + q * 8]);
    #pragma unroll
    for (int nt = 0; nt < 4; ++nt)
      bf[nt] = ld8(&Bs[(wn + nt * 16 + ln) * 32 + q * 8]);
    #pragma unroll
    for (int mt = 0; mt < 4; ++mt)
      #pragma unroll
      for (int nt = 0; nt < 4; ++nt)
        acc[mt][nt] = __builtin_amdgcn_mfma_f32_16x16x32_bf16(af[mt], bf[nt], acc[mt][nt], 0, 0, 0);
    __syncthreads();
  }
  #pragma unroll
  for (int nt = 0; nt < 4; ++nt){
    int gc = n0 + wn + nt * 16 + ln;
    float bv = bias[gc];
    #pragma unroll
    for (int mt = 0; mt < 4; ++mt){
      #pragma unroll
      for (int r = 0; r < 4; ++r){
        int gr = m0 + wm + mt * 16 + q * 4 + r;
        Cout[(size_t)gr * G3 + gc] = acc[mt][nt][r] + bv;
      }
    }
  }
}

// ---------------- phase 3: GRU — one launch per timestep ----------------
__global__ __launch_bounds__(384) void gru_step(
    const u16* __restrict__ whh, const float* __restrict__ bhh,
    const float* __restrict__ gi,
    u16* __restrict__ hhi, u16* __restrict__ hlo, int t, int tl){
  const int tid = threadIdx.x;
  const int wave = tid >> 6, lane = tid & 63;
  const int q = lane >> 4, ln = lane & 15;
  const int g = blockIdx.x & 7, s = blockIdx.x >> 3;

  __shared__ float gh[16 * 193];

  const int cur = t & 1, nxt = cur ^ 1;
  const size_t abase = (size_t)cur * BH + (size_t)(g * 16 + ln) * 512 + q * 8;

  bf16x8 ah[16];
  #pragma unroll
  for (int kk = 0; kk < 16; ++kk) ah[kk] = ld8(hhi + abase + kk * 32);

  f32x4 acc0 = {0.f,0.f,0.f,0.f}, acc1 = {0.f,0.f,0.f,0.f};
  {
    const int tt0 = wave * 2, tt1 = wave * 2 + 1;
    const int row0 = (tt0 >> 2) * 512 + s * 64 + (tt0 & 3) * 16 + ln;
    const int row1 = (tt1 >> 2) * 512 + s * 64 + (tt1 & 3) * 16 + ln;
    const u16* wp0 = whh + (size_t)row0 * 512 + q * 8;
    const u16* wp1 = whh + (size_t)row1 * 512 + q * 8;
    #pragma unroll
    for (int kk = 0; kk < 16; ++kk){
      bf16x8 w0 = ld8(wp0 + kk * 32);
      bf16x8 w1 = ld8(wp1 + kk * 32);
      bf16x8 al = ld8(hlo + abase + kk * 32);
      acc0 = __builtin_amdgcn_mfma_f32_16x16x32_bf16(ah[kk], w0, acc0, 0, 0, 0);
      acc1 = __builtin_amdgcn_mfma_f32_16x16x32_bf16(ah[kk], w1, acc1, 0, 0, 0);
      acc0 = __builtin_amdgcn_mfma_f32_16x16x32_bf16(al,     w0, acc0, 0, 0, 0);
      acc1 = __builtin_amdgcn_mfma_f32_16x16x32_bf16(al,     w1, acc1, 0, 0, 0);
    }
  }
  const int tile0 = wave * 2;
  #pragma unroll
  for (int r = 0; r < 4; ++r){
    gh[(q * 4 + r) * 193 +  tile0      * 16 + ln] = acc0[r];
    gh[(q * 4 + r) * 193 + (tile0 + 1) * 16 + ln] = acc1[r];
  }
  __syncthreads();
  #pragma unroll
  for (int it = 0; it < 3; ++it){
    int i = tid + it * 384;
    if (i < 1024){
      int b = i >> 6, hl = i & 63;
      float ghr = gh[b * 193 +       hl];
      float ghz = gh[b * 193 +  64 + hl];
      float ghn = gh[b * 193 + 128 + hl];
      size_t gib = ((size_t)tl * 128 + g * 16 + b) * 1536 + s * 64 + hl;
      float ir  = gi[gib];
      float iz  = gi[gib + 512];
      float inn = gi[gib + 1024];
      float bhr = bhh[       s * 64 + hl];
      float bhz = bhh[ 512 + s * 64 + hl];
      float bhn = bhh[1024 + s * 64 + hl];
      int hidx = (g * 16 + b) * 512 + s * 64 + hl;
      float hp = bf2f(hhi[(size_t)cur * BH + hidx]) + bf2f(hlo[(size_t)cur * BH + hidx]);
      float rr = 1.f / (1.f + expf(-(ir + ghr + bhr)));
      float zz = 1.f / (1.f + expf(-(iz + ghz + bhz)));
      float nn = tanhf(inn + rr * (ghn + bhn));
      float hn = (1.f - zz) * nn + zz * hp;
      u16 hi16 = f2bf(hn);
      float hif = bf2f(hi16);
      u16 lo16 = f2bf(hn - hif);
      hhi[(size_t)nxt * BH + hidx] = hi16;
      hlo[(size_t)nxt * BH + hidx] = lo16;
    }
  }
}

// ---------------- phase 4: out(fp32) = h @ cls_w^T + cls_b ----------------
__global__ __launch_bounds__(256) void cls_kernel(const u16* __restrict__ hhi,
    const u16* __restrict__ hlo,
    const float* __restrict__ cw, const float* __restrict__ cb, float* __restrict__ out){
  int idx = blockIdx.x * 256 + threadIdx.x;
  if (idx >= BB * CC) return;
  int b = idx / CC, c = idx % CC;
  const u16* hhp = hhi + (size_t)b * 512;   // h_final in buffer 0 (1024 is even)
  const u16* hlp = hlo + (size_t)b * 512;
  const float* wp = cw + (size_t)c * 512;
  float acc = cb[c];
  for (int k = 0; k < 512; ++k)
    acc += (bf2f(hhp[k]) + bf2f(hlp[k])) * wp[k];
  out[idx] = acc;   // fp32 output — reference computes in fp32
}

extern "C" void kernel_launch(void* const* d_in, const int* in_sizes, int n_in,
                              void* d_out, int out_size, void* d_ws, size_t ws_size,
                              hipStream_t stream){
  const int*  x      = (const int*)d_in[0];
  const void* conv_w = d_in[1];
  const void* conv_b = d_in[2];
  const void* w_ih   = d_in[3];
  const void* w_hh   = d_in[4];
  const void* b_ih   = d_in[5];
  const void* b_hh   = d_in[6];
  const void* cls_w  = d_in[7];
  const void* cls_b  = d_in[8];
  float* out = (float*)d_out;

  char* ws = (char*)d_ws;
  size_t off = 0;
  u32*   flag  = (u32*)(ws + off);  off += 256;   // [0]=float dtype, [64]=int width
  u32*   flagx = flag + 64;
  u16*   hhi   = (u16*)(ws + off);  off += (size_t)2 * BH * 2;   // 262,144
  u16*   hlo   = (u16*)(ws + off);  off += (size_t)2 * BH * 2;   // 262,144
  int*   xi    = (int*)(ws + off);  off += (size_t)BB * LL * 4;  // 524,288
  u16*   cwb   = (u16*)(ws + off);  off += (size_t)VH * 3 * 2;   // 1,572,864
  u16*   wihb  = (u16*)(ws + off);  off += (size_t)G3 * HH * 2;  // 1,572,864
  u16*   whhb  = (u16*)(ws + off);  off += (size_t)G3 * HH * 2;  // 1,572,864
  float* cbf   = (float*)(ws + off); off += (size_t)HH * 4;
  float* bihf  = (float*)(ws + off); off += (size_t)G3 * 4;
  float* bhhf  = (float*)(ws + off); off += (size_t)G3 * 4;
  float* clswf = (float*)(ws + off); off += (size_t)CC * HH * 4;
  float* clsbf = (float*)(ws + off); off += 256;
  const size_t fixed0 = off;                                      // ~5.9 MB

  const size_t tabs_bytes = (size_t)3 * VH * 2;                   // 1,572,864
  const size_t per_step   = (size_t)BB * HH * 2 + (size_t)BB * G3 * 4;  // 917,504

  int use_tabs = 1;
  int Tc = 1024;
  {
    size_t fixed = fixed0 + tabs_bytes;
    while (Tc > 1 && fixed + (size_t)Tc * per_step > ws_size) Tc >>= 1;
    if (fixed + (size_t)Tc * per_step > ws_size){
      use_tabs = 0;
      Tc = 1024;
      while (Tc > 1 && fixed0 + (size_t)Tc * per_step > ws_size) Tc >>= 1;
      if (fixed0 + (size_t)Tc * per_step > ws_size) return;  // ws too small: visible fail
    }
  }
  u16* tabs = nullptr;
  if (use_tabs){ tabs = (u16*)(ws + off); off += tabs_bytes; }
  u16*   seq = (u16*)(ws + off); off += (size_t)Tc * BB * HH * 2;
  float* gi  = (float*)(ws + off);

  hipMemsetAsync(hhi, 0, (size_t)4 * BH * 2, stream);   // zero both h double-buffers

  detect_dtype<<<dim3(1), 256, 0, stream>>>((const u16*)conv_b, flag);
  detect_int  <<<dim3(1), 256, 0, stream>>>(x, flagx);
  norm_x   <<<dim3((BB * LL + 255) / 256), 256, 0, stream>>>(x, xi, flagx);
  norm_bf16<<<dim3((VH * 3 + 255) / 256),  256, 0, stream>>>(conv_w, cwb,  VH * 3,  flag);
  norm_bf16<<<dim3((G3 * HH + 255) / 256), 256, 0, stream>>>(w_ih,  wihb, G3 * HH, flag);
  norm_bf16<<<dim3((G3 * HH + 255) / 256), 256, 0, stream>>>(w_hh,  whhb, G3 * HH, flag);
  norm_f32 <<<dim3((HH + 255) / 256),      256, 0, stream>>>(conv_b, cbf,   HH,      flag);
  norm_f32 <<<dim3((G3 + 255) / 256),      256, 0, stream>>>(b_ih,   bihf,  G3,      flag);
  norm_f32 <<<dim3((G3 + 255) / 256),      256, 0, stream>>>(b_hh,   bhhf,  G3,      flag);
  norm_f32 <<<dim3((CC * HH + 255) / 256), 256, 0, stream>>>(cls_w,  clswf, CC * HH, flag);
  norm_f32 <<<dim3(1),                     256, 0, stream>>>(cls_b,  clsbf, CC,      flag);

  if (use_tabs)
    prep_tables<<<dim3((VH + 255) / 256), 256, 0, stream>>>(cwb, tabs);

  const int nchunks = LL / Tc;
  for (int c = 0; c < nchunks; ++c){
    int t0 = c * Tc;
    embed_kernel<<<dim3(Tc * BB / 4), 256, 0, stream>>>(xi, tabs, cwb, cbf, seq, t0 * BB);
    gemm_gi     <<<dim3(12, Tc),      256, 0, stream>>>(seq, wihb, bihf, gi);
    for (int tl = 0; tl < Tc; ++tl)
      gru_step<<<dim3(64), 384, 0, stream>>>(whhb, bhhf, gi, hhi, hlo, t0 + tl, tl);
  }
  cls_kernel<<<dim3(10), 256, 0, stream>>>(hhi, hlo, clswf, clsbf, out);
}